// Round 12
// baseline (290.352 us; speedup 1.0000x reference)
//
#include <hip/hip_runtime.h>
#include <hip/hip_bf16.h>

typedef __bf16 bf16x8 __attribute__((ext_vector_type(8)));
typedef __bf16 bf16x4 __attribute__((ext_vector_type(4)));
typedef float  f32x4  __attribute__((ext_vector_type(4)));

#define MFMA16(a, b, c) __builtin_amdgcn_mfma_f32_16x16x32_bf16((a), (b), (c), 0, 0, 0)
#define GLD16(g, l)                                                              \
    __builtin_amdgcn_global_load_lds(                                            \
        (const __attribute__((address_space(1))) void*)(g),                      \
        (__attribute__((address_space(3))) void*)(l), 16, 0, 0)

// ---------------- fp32 -> bf16 convert (vectorized, grid-stride) ----------------
__global__ __launch_bounds__(256) void cvt_f32_bf16(const float* __restrict__ in,
                                                    __bf16* __restrict__ out, int n) {
    int stride = gridDim.x * blockDim.x * 4;
    for (int i = (blockIdx.x * blockDim.x + threadIdx.x) * 4; i < n; i += stride) {
        float4 v = *(const float4*)(in + i);
        bf16x4 o;
        o[0] = (__bf16)v.x; o[1] = (__bf16)v.y; o[2] = (__bf16)v.z; o[3] = (__bf16)v.w;
        *(bf16x4*)(out + i) = o;
    }
}

// ---------------- QKV GEMM (m97 structure): [8192,1024] @ [3072,1024]^T + bias ----
// Q is pre-scaled by 1/sqrt(D) = 0.125 (exact power of 2 -> no bf16 precision loss).
__global__ __launch_bounds__(256, 2) void qkv_gemm(const __bf16* __restrict__ X,
                                                   const __bf16* __restrict__ W,
                                                   const float* __restrict__ bias,
                                                   __bf16* __restrict__ Qo,
                                                   __bf16* __restrict__ Ko,
                                                   __bf16* __restrict__ VTo) {
    const int KD = 1024;
    __shared__ __align__(16) __bf16 As[128 * 32];
    __shared__ __align__(16) __bf16 Bs[128 * 32];
    const int tid = threadIdx.x;
    const int lane = tid & 63, w = tid >> 6;
    const int lr = lane & 15, lg = lane >> 4;
    const int row0 = blockIdx.y * 128, col0 = blockIdx.x * 128;
    const int wrow = (w >> 1) * 64, wcol = (w & 1) * 64;
    f32x4 acc[4][4] = {};
    const int c0 = tid, c1 = tid + 256;
    const __bf16* ga0 = X + (size_t)(row0 + (c0 >> 2)) * KD + (c0 & 3) * 8;
    const __bf16* ga1 = X + (size_t)(row0 + (c1 >> 2)) * KD + (c1 & 3) * 8;
    const __bf16* gb0 = W + (size_t)(col0 + (c0 >> 2)) * KD + (c0 & 3) * 8;
    const __bf16* gb1 = W + (size_t)(col0 + (c1 >> 2)) * KD + (c1 & 3) * 8;
    for (int k0 = 0; k0 < KD; k0 += 32) {
        __syncthreads();
        GLD16(ga0 + k0, As + c0 * 8);
        GLD16(ga1 + k0, As + c1 * 8);
        GLD16(gb0 + k0, Bs + c0 * 8);
        GLD16(gb1 + k0, Bs + c1 * 8);
        __syncthreads();
        bf16x8 a[4], b[4];
#pragma unroll
        for (int mi = 0; mi < 4; mi++)
            a[mi] = *(const bf16x8*)&As[(wrow + mi * 16 + lr) * 32 + lg * 8];
#pragma unroll
        for (int ni = 0; ni < 4; ni++)
            b[ni] = *(const bf16x8*)&Bs[(wcol + ni * 16 + lr) * 32 + lg * 8];
#pragma unroll
        for (int mi = 0; mi < 4; mi++)
#pragma unroll
            for (int ni = 0; ni < 4; ni++)
                acc[mi][ni] = MFMA16(a[mi], b[ni], acc[mi][ni]);
    }
#pragma unroll
    for (int mi = 0; mi < 4; mi++)
#pragma unroll
        for (int ni = 0; ni < 4; ni++)
#pragma unroll
            for (int r = 0; r < 4; r++) {
                int m = row0 + wrow + mi * 16 + lg * 4 + r;  // token row
                int n = col0 + wcol + ni * 16 + lr;          // channel (0..3071)
                float v = acc[mi][ni][r] + bias[n];
                int b_ = m >> 11, t = m & 2047;
                int sec = n >> 10, c = n & 1023;
                int h = c >> 6, d = c & 63;
                int bh = b_ * 16 + h;
                if (sec == 0)      Qo[(size_t)(bh * 2048 + t) * 64 + d] = (__bf16)(v * 0.125f);
                else if (sec == 1) Ko[(size_t)(bh * 2048 + t) * 64 + d] = (__bf16)v;
                else               VTo[(size_t)(bh * 64 + d) * 2048 + t] = (__bf16)v;
            }
}

// ---------------- causal flash attention (r10 structure, VGPR clamp removed) -----
// 2048 blocks x 4 waves = 8192 wave-units of ~(p+1)/2 tiles; ~4096 resident at
// natural VGPR (~110-130 < 128), 2x backlog, longest-p-first. Block = both
// k-halves of TWO ADJACENT panels {2p, 2p+1} (same nkb=p+1): waves (0,2) sweep
// the low half in lockstep, (1,3) the high half -> L1 sharing (the r2/r6 L=4.3
// config). No k-loop barriers; end-merge via conflict-free [lane*49] f32 LDS
// buffer. V-loads hoisted before the P-LDS round-trip. NO launch_bounds clamp
// (r10's mistake: min-waves=4 forced VGPR=64 -> spills).
__global__ __launch_bounds__(256) void attn_kernel(const __bf16* __restrict__ Q,
                                                   const __bf16* __restrict__ Km,
                                                   const __bf16* __restrict__ VT,
                                                   __bf16* __restrict__ ATT) {
    const int T = 2048, D = 64;
    __shared__ __align__(16) char smem[25088];  // plds 4x4352; merge 2x12544 (alias)
    const int lane = threadIdx.x & 63, w = threadIdx.x >> 6;
    const int lr = lane & 15, lg = lane >> 4;
    // XCD x owns bh [8x, 8x+8); within, pairs sorted longest-first
    const int orig = blockIdx.x;
    const int xcd = orig & 7, rank = orig >> 3;        // rank 0..255
    const int bh = xcd * 8 + (rank >> 5);
    const int p = 31 - (rank & 31);                    // pair index, longest first
    const int j = 2 * p + (w >> 1);                    // this wave's panel
    const int h = w & 1;                               // k-half
    const int qrow0 = j * 32;
    const int b_ = bh >> 4, hh = bh & 15;
    __bf16* plds = (__bf16*)(smem + w * 4352);         // [32][68] per-wave slab
    float*  mbuf = (float*)(smem + (w >> 1) * 12544);  // [64][49] per-panel merge
    const __bf16* Qp = Q + (size_t)bh * T * D;
    const __bf16* Kp = Km + (size_t)bh * T * D;
    const __bf16* Vp = VT + (size_t)bh * D * T;

    bf16x8 qa[2][2];
#pragma unroll
    for (int qt = 0; qt < 2; qt++)
#pragma unroll
        for (int dk = 0; dk < 2; dk++)
            qa[qt][dk] = *(const bf16x8*)(Qp + (size_t)(qrow0 + qt * 16 + lr) * D + dk * 32 + lg * 8);

    float mrow[2][4], lsum[2][4];
#pragma unroll
    for (int qt = 0; qt < 2; qt++)
#pragma unroll
        for (int r = 0; r < 4; r++) { mrow[qt][r] = -1e30f; lsum[qt][r] = 0.f; }
    f32x4 o[2][4] = {};

    const int nkb = p + 1;                 // same for both panels of the pair
    const int mid = nkb >> 1;
    const int lo = h ? mid : 0;
    const int hi = h ? nkb : mid;
    for (int kt0 = lo; kt0 < hi; ++kt0) {
        const int kb = kt0 * 64;
        bf16x8 kf[4][2];
#pragma unroll
        for (int kt = 0; kt < 4; kt++)
#pragma unroll
            for (int dk = 0; dk < 2; dk++)
                kf[kt][dk] = *(const bf16x8*)(Kp + (size_t)(kb + kt * 16 + lr) * D + dk * 32 + lg * 8);
        f32x4 s[2][4] = {};
#pragma unroll
        for (int qt = 0; qt < 2; qt++)
#pragma unroll
            for (int kt = 0; kt < 4; kt++)
#pragma unroll
                for (int dk = 0; dk < 2; dk++)
                    s[qt][kt] = MFMA16(qa[qt][dk], kf[kt][dk], s[qt][kt]);

        // mask + per-lane local max (Q pre-scaled; no cross-lane ops on common path)
        float lmax[2][4];
        int flag = 0;
#pragma unroll
        for (int qt = 0; qt < 2; qt++)
#pragma unroll
            for (int r = 0; r < 4; r++) {
                const int qq = qrow0 + qt * 16 + lg * 4 + r;
                float mt = -1e30f;
#pragma unroll
                for (int kt = 0; kt < 4; kt++) {
                    float v = (kb + kt * 16 + lr <= qq) ? s[qt][kt][r] : -1e30f;
                    s[qt][kt][r] = v;
                    mt = fmaxf(mt, v);
                }
                lmax[qt][r] = mt;
                flag |= (mt > mrow[qt][r] + 8.0f) ? 1 : 0;
            }

        // defer-max (T13): full reduce + rescale only when some row grew > 8
        if (__any(flag)) {
#pragma unroll
            for (int qt = 0; qt < 2; qt++)
#pragma unroll
                for (int r = 0; r < 4; r++) {
                    float mt = lmax[qt][r];
#pragma unroll
                    for (int off = 1; off < 16; off <<= 1)
                        mt = fmaxf(mt, __shfl_xor(mt, off));
                    float mnew = fmaxf(mrow[qt][r], mt);
                    float al = __expf(mrow[qt][r] - mnew);
                    mrow[qt][r] = mnew;
                    lsum[qt][r] *= al;
#pragma unroll
                    for (int dt = 0; dt < 4; dt++) o[qt][dt][r] *= al;
                }
        }

        // exp + per-lane partial row-sum
#pragma unroll
        for (int qt = 0; qt < 2; qt++)
#pragma unroll
            for (int r = 0; r < 4; r++) {
                float rs = 0.f;
#pragma unroll
                for (int kt = 0; kt < 4; kt++) {
                    float p_ = __expf(s[qt][kt][r] - mrow[qt][r]);
                    s[qt][kt][r] = p_;
                    rs += p_;
                }
                lsum[qt][r] += rs;
            }

        // hoist V-loads: issue before the P-LDS round-trip (ds ops cover latency)
        bf16x8 vf[2][4];
#pragma unroll
        for (int kh = 0; kh < 2; kh++)
#pragma unroll
            for (int dt = 0; dt < 4; dt++)
                vf[kh][dt] = *(const bf16x8*)(Vp + (size_t)(dt * 16 + lr) * T + kb + kh * 32 + lg * 8);

        // P -> padded LDS slab (conflict-free) -> A-fragments
#pragma unroll
        for (int qt = 0; qt < 2; qt++)
#pragma unroll
            for (int kt = 0; kt < 4; kt++)
#pragma unroll
                for (int r = 0; r < 4; r++)
                    plds[(qt * 16 + lg * 4 + r) * 68 + kt * 16 + lr] = (__bf16)s[qt][kt][r];

        bf16x8 pa[2][2];
#pragma unroll
        for (int qt = 0; qt < 2; qt++)
#pragma unroll
            for (int kh = 0; kh < 2; kh++)
                pa[qt][kh] = *(const bf16x8*)&plds[(qt * 16 + lr) * 68 + kh * 32 + lg * 8];

#pragma unroll
        for (int kh = 0; kh < 2; kh++)
#pragma unroll
            for (int qt = 0; qt < 2; qt++)
#pragma unroll
                for (int dt = 0; dt < 4; dt++)
                    o[qt][dt] = MFMA16(pa[qt][kh], vf[kh][dt], o[qt][dt]);
    }

    // reduce partial row-sums across 16-lane groups (raw l, not inverted yet)
#pragma unroll
    for (int qt = 0; qt < 2; qt++)
#pragma unroll
        for (int r = 0; r < 4; r++) {
            float rs = lsum[qt][r];
#pragma unroll
            for (int off = 1; off < 16; off <<= 1)
                rs += __shfl_xor(rs, off);
            lsum[qt][r] = rs;
        }

    // ---- merge the two k-halves of each panel (end-of-kernel coupling only) ----
    __syncthreads();                          // all waves done with plds
    if (h == 1) {                             // publish partial state
        float* mb = mbuf + lane * 49;
#pragma unroll
        for (int qt = 0; qt < 2; qt++)
#pragma unroll
            for (int dt = 0; dt < 4; dt++)
#pragma unroll
                for (int r = 0; r < 4; r++)
                    mb[qt * 16 + dt * 4 + r] = o[qt][dt][r];
#pragma unroll
        for (int qt = 0; qt < 2; qt++)
#pragma unroll
            for (int r = 0; r < 4; r++) {
                mb[32 + qt * 4 + r] = mrow[qt][r];
                mb[40 + qt * 4 + r] = lsum[qt][r];
            }
    }
    __syncthreads();
    if (h == 0) {                             // merge + normalize + store
        const float* mb = mbuf + lane * 49;
#pragma unroll
        for (int qt = 0; qt < 2; qt++)
#pragma unroll
            for (int r = 0; r < 4; r++) {
                float m1 = mb[32 + qt * 4 + r];
                float l1 = mb[40 + qt * 4 + r];
                float m = fmaxf(mrow[qt][r], m1);
                float a0 = __expf(mrow[qt][r] - m);
                float a1 = __expf(m1 - m);
                float inv = 1.0f / (lsum[qt][r] * a0 + l1 * a1);
                int qq = qrow0 + qt * 16 + lg * 4 + r;
#pragma unroll
                for (int dt = 0; dt < 4; dt++) {
                    int dd = dt * 16 + lr;
                    float v1 = mb[qt * 16 + dt * 4 + r];
                    float val = (o[qt][dt][r] * a0 + v1 * a1) * inv;
                    ATT[(size_t)(b_ * 2048 + qq) * 1024 + hh * 64 + dd] = (__bf16)val;
                }
            }
    }
}

// ---------------- proj GEMM (m97 structure): [8192,1024] @ [1024,1024]^T + bias ----
__global__ __launch_bounds__(256, 2) void proj_gemm(const __bf16* __restrict__ A,
                                                    const __bf16* __restrict__ W,
                                                    const float* __restrict__ bias,
                                                    float* __restrict__ out) {
    const int KD = 1024;
    __shared__ __align__(16) __bf16 As[128 * 32];
    __shared__ __align__(16) __bf16 Bs[128 * 32];
    const int tid = threadIdx.x;
    const int lane = tid & 63, w = tid >> 6;
    const int lr = lane & 15, lg = lane >> 4;
    const int row0 = blockIdx.y * 128, col0 = blockIdx.x * 128;
    const int wrow = (w >> 1) * 64, wcol = (w & 1) * 64;
    f32x4 acc[4][4] = {};
    const int c0 = tid, c1 = tid + 256;
    const __bf16* ga0 = A + (size_t)(row0 + (c0 >> 2)) * KD + (c0 & 3) * 8;
    const __bf16* ga1 = A + (size_t)(row0 + (c1 >> 2)) * KD + (c1 & 3) * 8;
    const __bf16* gb0 = W + (size_t)(col0 + (c0 >> 2)) * KD + (c0 & 3) * 8;
    const __bf16* gb1 = W + (size_t)(col0 + (c1 >> 2)) * KD + (c1 & 3) * 8;
    for (int k0 = 0; k0 < KD; k0 += 32) {
        __syncthreads();
        GLD16(ga0 + k0, As + c0 * 8);
        GLD16(ga1 + k0, As + c1 * 8);
        GLD16(gb0 + k0, Bs + c0 * 8);
        GLD16(gb1 + k0, Bs + c1 * 8);
        __syncthreads();
        bf16x8 a[4], b[4];
#pragma unroll
        for (int mi = 0; mi < 4; mi++)
            a[mi] = *(const bf16x8*)&As[(wrow + mi * 16 + lr) * 32 + lg * 8];
#pragma unroll
        for (int ni = 0; ni < 4; ni++)
            b[ni] = *(const bf16x8*)&Bs[(wcol + ni * 16 + lr) * 32 + lg * 8];
#pragma unroll
        for (int mi = 0; mi < 4; mi++)
#pragma unroll
            for (int ni = 0; ni < 4; ni++)
                acc[mi][ni] = MFMA16(a[mi], b[ni], acc[mi][ni]);
    }
#pragma unroll
    for (int mi = 0; mi < 4; mi++)
#pragma unroll
        for (int ni = 0; ni < 4; ni++)
#pragma unroll
            for (int r = 0; r < 4; r++) {
                int m = row0 + wrow + mi * 16 + lg * 4 + r;
                int n = col0 + wcol + ni * 16 + lr;
                out[(size_t)m * 1024 + n] = acc[mi][ni][r] + bias[n];
            }
}

extern "C" void kernel_launch(void* const* d_in, const int* in_sizes, int n_in,
                              void* d_out, int out_size, void* d_ws, size_t ws_size,
                              hipStream_t stream) {
    const float* x      = (const float*)d_in[0];
    const float* qkv_w  = (const float*)d_in[1];
    const float* qkv_b  = (const float*)d_in[2];
    const float* proj_w = (const float*)d_in[3];
    const float* proj_b = (const float*)d_in[4];
    float* out = (float*)d_out;
    char* ws = (char*)d_ws;

    // workspace layout (72 MB total)
    __bf16* xb    = (__bf16*)(ws);                         // 16 MB (reused as attb)
    __bf16* wqkv  = (__bf16*)(ws + 16777216);              //  6 MB
    __bf16* wproj = (__bf16*)(ws + 23068672);              //  2 MB
    __bf16* qb    = (__bf16*)(ws + 25165824);              // 16 MB
    __bf16* kb    = (__bf16*)(ws + 41943040);              // 16 MB
    __bf16* vtb   = (__bf16*)(ws + 58720256);              // 16 MB
    __bf16* attb  = xb;                                    // alias: x dead after QKV

    cvt_f32_bf16<<<2048, 256, 0, stream>>>(x,      xb,    4 * 2048 * 1024);
    cvt_f32_bf16<<<768,  256, 0, stream>>>(qkv_w,  wqkv,  3072 * 1024);
    cvt_f32_bf16<<<256,  256, 0, stream>>>(proj_w, wproj, 1024 * 1024);
    qkv_gemm<<<dim3(24, 64), 256, 0, stream>>>(xb, wqkv, qkv_b, qb, kb, vtb);
    attn_kernel<<<2048, 256, 0, stream>>>(qb, kb, vtb, attb);
    proj_gemm<<<dim3(8, 64), 256, 0, stream>>>(attb, wproj, proj_b, out);
}

// Round 13
// 284.533 us; speedup vs baseline: 1.0205x; 1.0205x over previous
//
#include <hip/hip_runtime.h>
#include <hip/hip_bf16.h>

typedef __bf16 bf16x8 __attribute__((ext_vector_type(8)));
typedef __bf16 bf16x4 __attribute__((ext_vector_type(4)));
typedef float  f32x4  __attribute__((ext_vector_type(4)));

#define MFMA16(a, b, c) __builtin_amdgcn_mfma_f32_16x16x32_bf16((a), (b), (c), 0, 0, 0)
#define GLD16(g, l)                                                              \
    __builtin_amdgcn_global_load_lds(                                            \
        (const __attribute__((address_space(1))) void*)(g),                      \
        (__attribute__((address_space(3))) void*)(l), 16, 0, 0)

// ---------------- fp32 -> bf16 convert (vectorized, grid-stride) ----------------
__global__ __launch_bounds__(256) void cvt_f32_bf16(const float* __restrict__ in,
                                                    __bf16* __restrict__ out, int n) {
    int stride = gridDim.x * blockDim.x * 4;
    for (int i = (blockIdx.x * blockDim.x + threadIdx.x) * 4; i < n; i += stride) {
        float4 v = *(const float4*)(in + i);
        bf16x4 o;
        o[0] = (__bf16)v.x; o[1] = (__bf16)v.y; o[2] = (__bf16)v.z; o[3] = (__bf16)v.w;
        *(bf16x4*)(out + i) = o;
    }
}

// ---------------- QKV GEMM (m97 structure + XCD-chunked swizzle) -----------------
// Flat grid 1536; XCD x owns col-tiles [3x, 3x+3) x all 64 row-tiles -> its W
// working set (3 x 256KB) stays L2-resident while X streams. Q pre-scaled 0.125.
__global__ __launch_bounds__(256, 2) void qkv_gemm(const __bf16* __restrict__ X,
                                                   const __bf16* __restrict__ W,
                                                   const float* __restrict__ bias,
                                                   __bf16* __restrict__ Qo,
                                                   __bf16* __restrict__ Ko,
                                                   __bf16* __restrict__ VTo) {
    const int KD = 1024;
    __shared__ __align__(16) __bf16 As[128 * 32];
    __shared__ __align__(16) __bf16 Bs[128 * 32];
    const int tid = threadIdx.x;
    const int lane = tid & 63, w = tid >> 6;
    const int lr = lane & 15, lg = lane >> 4;
    const int orig = blockIdx.x;                       // 0..1535
    const int wgid = (orig & 7) * 192 + (orig >> 3);   // bijective (1536 % 8 == 0)
    const int row0 = (wgid & 63) * 128, col0 = (wgid >> 6) * 128;
    const int wrow = (w >> 1) * 64, wcol = (w & 1) * 64;
    f32x4 acc[4][4] = {};
    const int c0 = tid, c1 = tid + 256;
    const __bf16* ga0 = X + (size_t)(row0 + (c0 >> 2)) * KD + (c0 & 3) * 8;
    const __bf16* ga1 = X + (size_t)(row0 + (c1 >> 2)) * KD + (c1 & 3) * 8;
    const __bf16* gb0 = W + (size_t)(col0 + (c0 >> 2)) * KD + (c0 & 3) * 8;
    const __bf16* gb1 = W + (size_t)(col0 + (c1 >> 2)) * KD + (c1 & 3) * 8;
    for (int k0 = 0; k0 < KD; k0 += 32) {
        __syncthreads();
        GLD16(ga0 + k0, As + c0 * 8);
        GLD16(ga1 + k0, As + c1 * 8);
        GLD16(gb0 + k0, Bs + c0 * 8);
        GLD16(gb1 + k0, Bs + c1 * 8);
        __syncthreads();
        bf16x8 a[4], b[4];
#pragma unroll
        for (int mi = 0; mi < 4; mi++)
            a[mi] = *(const bf16x8*)&As[(wrow + mi * 16 + lr) * 32 + lg * 8];
#pragma unroll
        for (int ni = 0; ni < 4; ni++)
            b[ni] = *(const bf16x8*)&Bs[(wcol + ni * 16 + lr) * 32 + lg * 8];
#pragma unroll
        for (int mi = 0; mi < 4; mi++)
#pragma unroll
            for (int ni = 0; ni < 4; ni++)
                acc[mi][ni] = MFMA16(a[mi], b[ni], acc[mi][ni]);
    }
#pragma unroll
    for (int mi = 0; mi < 4; mi++)
#pragma unroll
        for (int ni = 0; ni < 4; ni++)
#pragma unroll
            for (int r = 0; r < 4; r++) {
                int m = row0 + wrow + mi * 16 + lg * 4 + r;  // token row
                int n = col0 + wcol + ni * 16 + lr;          // channel (0..3071)
                float v = acc[mi][ni][r] + bias[n];
                int b_ = m >> 11, t = m & 2047;
                int sec = n >> 10, c = n & 1023;
                int h = c >> 6, d = c & 63;
                int bh = b_ * 16 + h;
                if (sec == 0)      Qo[(size_t)(bh * 2048 + t) * 64 + d] = (__bf16)(v * 0.125f);
                else if (sec == 1) Ko[(size_t)(bh * 2048 + t) * 64 + d] = (__bf16)v;
                else               VTo[(size_t)(bh * 64 + d) * 2048 + t] = (__bf16)v;
            }
}

// ---------------- causal flash attention (champion structure, KBLK=128) ----------
// 512 blocks x 4 waves = 2048 uniform independent waves; wave owns q-tile pair
// {idx, 63-idx} = 17 k-tiles of 128 (vs 33 of 64): halves the serial tile-chain
// that floors the kernel (L is dep-chain-bound; per-tile work amortizes sub-2x).
// QK computed in two register-reusing 64-halves to cap VGPR (~200 < 256 -> the
// 2 waves/SIMD we need). No k-loop barriers. Padded P slab [32][136].
__global__ __launch_bounds__(256) void attn_kernel(const __bf16* __restrict__ Q,
                                                   const __bf16* __restrict__ Km,
                                                   const __bf16* __restrict__ VT,
                                                   __bf16* __restrict__ ATT) {
    const int T = 2048, D = 64;
    __shared__ __align__(16) __bf16 plds[4][32][136];  // padded: conflict-free
    const int lane = threadIdx.x & 63, w = threadIdx.x >> 6;
    const int lr = lane & 15, lg = lane >> 4;
    // bijective XCD swizzle (512 % 8 == 0): each XCD owns 8 contiguous bh
    const int orig = blockIdx.x;
    const int wgid = (orig & 7) * 64 + (orig >> 3);
    const int bh = wgid >> 3;                 // 8 blocks per bh
    const int idx = (wgid & 7) * 4 + w;       // 0..31
    const int b_ = bh >> 4, hh = bh & 15;
    const __bf16* Qp = Q + (size_t)bh * T * D;
    const __bf16* Kp = Km + (size_t)bh * T * D;
    const __bf16* Vp = VT + (size_t)bh * D * T;

    for (int ph = 0; ph < 2; ++ph) {
        const int j = ph ? 63 - idx : idx;
        const int qrow0 = j * 32;
        bf16x8 qa[2][2];
#pragma unroll
        for (int qt = 0; qt < 2; qt++)
#pragma unroll
            for (int dk = 0; dk < 2; dk++)
                qa[qt][dk] = *(const bf16x8*)(Qp + (size_t)(qrow0 + qt * 16 + lr) * D + dk * 32 + lg * 8);

        float mrow[2][4], lsum[2][4];
#pragma unroll
        for (int qt = 0; qt < 2; qt++)
#pragma unroll
            for (int r = 0; r < 4; r++) { mrow[qt][r] = -1e30f; lsum[qt][r] = 0.f; }
        f32x4 o[2][4] = {};

        const int nkb = ((j * 32 + 31) >> 7) + 1;   // 128-wide k-tiles
        for (int kt0 = 0; kt0 < nkb; ++kt0) {
            const int kb = kt0 * 128;
            f32x4 s[2][8] = {};
            // QK in two 64-halves, reusing one kf register block
            {
                bf16x8 kf[4][2];
#pragma unroll
                for (int kt = 0; kt < 4; kt++)
#pragma unroll
                    for (int dk = 0; dk < 2; dk++)
                        kf[kt][dk] = *(const bf16x8*)(Kp + (size_t)(kb + kt * 16 + lr) * D + dk * 32 + lg * 8);
#pragma unroll
                for (int qt = 0; qt < 2; qt++)
#pragma unroll
                    for (int kt = 0; kt < 4; kt++)
#pragma unroll
                        for (int dk = 0; dk < 2; dk++)
                            s[qt][kt] = MFMA16(qa[qt][dk], kf[kt][dk], s[qt][kt]);
            }
            {
                bf16x8 kf[4][2];
#pragma unroll
                for (int kt = 0; kt < 4; kt++)
#pragma unroll
                    for (int dk = 0; dk < 2; dk++)
                        kf[kt][dk] = *(const bf16x8*)(Kp + (size_t)(kb + 64 + kt * 16 + lr) * D + dk * 32 + lg * 8);
#pragma unroll
                for (int qt = 0; qt < 2; qt++)
#pragma unroll
                    for (int kt = 0; kt < 4; kt++)
#pragma unroll
                        for (int dk = 0; dk < 2; dk++)
                            s[qt][4 + kt] = MFMA16(qa[qt][dk], kf[kt][dk], s[qt][4 + kt]);
            }

            // mask + per-lane local max (Q pre-scaled; no cross-lane common path)
            float lmax[2][4];
            int flag = 0;
#pragma unroll
            for (int qt = 0; qt < 2; qt++)
#pragma unroll
                for (int r = 0; r < 4; r++) {
                    const int qq = qrow0 + qt * 16 + lg * 4 + r;
                    float mt = -1e30f;
#pragma unroll
                    for (int kt = 0; kt < 8; kt++) {
                        float v = (kb + kt * 16 + lr <= qq) ? s[qt][kt][r] : -1e30f;
                        s[qt][kt][r] = v;
                        mt = fmaxf(mt, v);
                    }
                    lmax[qt][r] = mt;
                    flag |= (mt > mrow[qt][r] + 8.0f) ? 1 : 0;
                }

            // defer-max (T13): full reduce + rescale only when some row grew > 8
            if (__any(flag)) {
#pragma unroll
                for (int qt = 0; qt < 2; qt++)
#pragma unroll
                    for (int r = 0; r < 4; r++) {
                        float mt = lmax[qt][r];
#pragma unroll
                        for (int off = 1; off < 16; off <<= 1)
                            mt = fmaxf(mt, __shfl_xor(mt, off));
                        float mnew = fmaxf(mrow[qt][r], mt);
                        float al = __expf(mrow[qt][r] - mnew);
                        mrow[qt][r] = mnew;
                        lsum[qt][r] *= al;
#pragma unroll
                        for (int dt = 0; dt < 4; dt++) o[qt][dt][r] *= al;
                    }
            }

            // exp + per-lane partial row-sum
#pragma unroll
            for (int qt = 0; qt < 2; qt++)
#pragma unroll
                for (int r = 0; r < 4; r++) {
                    float rs = 0.f;
#pragma unroll
                    for (int kt = 0; kt < 8; kt++) {
                        float p = __expf(s[qt][kt][r] - mrow[qt][r]);
                        s[qt][kt][r] = p;
                        rs += p;
                    }
                    lsum[qt][r] += rs;
                }

            // P -> padded LDS slab (conflict-free) -> A-fragments
#pragma unroll
            for (int qt = 0; qt < 2; qt++)
#pragma unroll
                for (int kt = 0; kt < 8; kt++)
#pragma unroll
                    for (int r = 0; r < 4; r++)
                        plds[w][qt * 16 + lg * 4 + r][kt * 16 + lr] = (__bf16)s[qt][kt][r];

            // PV over 4 k-slots of 32
#pragma unroll
            for (int ks = 0; ks < 4; ks++) {
                bf16x8 vf[4];
#pragma unroll
                for (int dt = 0; dt < 4; dt++)
                    vf[dt] = *(const bf16x8*)(Vp + (size_t)(dt * 16 + lr) * T + kb + ks * 32 + lg * 8);
                bf16x8 pa[2];
#pragma unroll
                for (int qt = 0; qt < 2; qt++)
                    pa[qt] = *(const bf16x8*)&plds[w][qt * 16 + lr][ks * 32 + lg * 8];
#pragma unroll
                for (int qt = 0; qt < 2; qt++)
#pragma unroll
                    for (int dt = 0; dt < 4; dt++)
                        o[qt][dt] = MFMA16(pa[qt], vf[dt], o[qt][dt]);
            }
        }

        // final row-sum reduce (once per panel) + normalize + store
#pragma unroll
        for (int qt = 0; qt < 2; qt++)
#pragma unroll
            for (int r = 0; r < 4; r++) {
                float rs = lsum[qt][r];
#pragma unroll
                for (int off = 1; off < 16; off <<= 1)
                    rs += __shfl_xor(rs, off);
                lsum[qt][r] = 1.0f / rs;
            }
#pragma unroll
        for (int qt = 0; qt < 2; qt++)
#pragma unroll
            for (int dt = 0; dt < 4; dt++)
#pragma unroll
                for (int r = 0; r < 4; r++) {
                    int qq = qrow0 + qt * 16 + lg * 4 + r;
                    int dd = dt * 16 + lr;
                    float val = o[qt][dt][r] * lsum[qt][r];
                    ATT[(size_t)(b_ * 2048 + qq) * 1024 + hh * 64 + dd] = (__bf16)val;
                }
    }
}

// ---------------- proj GEMM (m97 structure + XCD-chunked swizzle) ----------------
__global__ __launch_bounds__(256, 2) void proj_gemm(const __bf16* __restrict__ A,
                                                    const __bf16* __restrict__ W,
                                                    const float* __restrict__ bias,
                                                    float* __restrict__ out) {
    const int KD = 1024;
    __shared__ __align__(16) __bf16 As[128 * 32];
    __shared__ __align__(16) __bf16 Bs[128 * 32];
    const int tid = threadIdx.x;
    const int lane = tid & 63, w = tid >> 6;
    const int lr = lane & 15, lg = lane >> 4;
    const int orig = blockIdx.x;                       // 0..511
    const int wgid = (orig & 7) * 64 + (orig >> 3);    // XCD x owns col-tile x
    const int row0 = (wgid & 63) * 128, col0 = (wgid >> 6) * 128;
    const int wrow = (w >> 1) * 64, wcol = (w & 1) * 64;
    f32x4 acc[4][4] = {};
    const int c0 = tid, c1 = tid + 256;
    const __bf16* ga0 = A + (size_t)(row0 + (c0 >> 2)) * KD + (c0 & 3) * 8;
    const __bf16* ga1 = A + (size_t)(row0 + (c1 >> 2)) * KD + (c1 & 3) * 8;
    const __bf16* gb0 = W + (size_t)(col0 + (c0 >> 2)) * KD + (c0 & 3) * 8;
    const __bf16* gb1 = W + (size_t)(col0 + (c1 >> 2)) * KD + (c1 & 3) * 8;
    for (int k0 = 0; k0 < KD; k0 += 32) {
        __syncthreads();
        GLD16(ga0 + k0, As + c0 * 8);
        GLD16(ga1 + k0, As + c1 * 8);
        GLD16(gb0 + k0, Bs + c0 * 8);
        GLD16(gb1 + k0, Bs + c1 * 8);
        __syncthreads();
        bf16x8 a[4], b[4];
#pragma unroll
        for (int mi = 0; mi < 4; mi++)
            a[mi] = *(const bf16x8*)&As[(wrow + mi * 16 + lr) * 32 + lg * 8];
#pragma unroll
        for (int ni = 0; ni < 4; ni++)
            b[ni] = *(const bf16x8*)&Bs[(wcol + ni * 16 + lr) * 32 + lg * 8];
#pragma unroll
        for (int mi = 0; mi < 4; mi++)
#pragma unroll
            for (int ni = 0; ni < 4; ni++)
                acc[mi][ni] = MFMA16(a[mi], b[ni], acc[mi][ni]);
    }
#pragma unroll
    for (int mi = 0; mi < 4; mi++)
#pragma unroll
        for (int ni = 0; ni < 4; ni++)
#pragma unroll
            for (int r = 0; r < 4; r++) {
                int m = row0 + wrow + mi * 16 + lg * 4 + r;
                int n = col0 + wcol + ni * 16 + lr;
                out[(size_t)m * 1024 + n] = acc[mi][ni][r] + bias[n];
            }
}

extern "C" void kernel_launch(void* const* d_in, const int* in_sizes, int n_in,
                              void* d_out, int out_size, void* d_ws, size_t ws_size,
                              hipStream_t stream) {
    const float* x      = (const float*)d_in[0];
    const float* qkv_w  = (const float*)d_in[1];
    const float* qkv_b  = (const float*)d_in[2];
    const float* proj_w = (const float*)d_in[3];
    const float* proj_b = (const float*)d_in[4];
    float* out = (float*)d_out;
    char* ws = (char*)d_ws;

    // workspace layout (72 MB total)
    __bf16* xb    = (__bf16*)(ws);                         // 16 MB (reused as attb)
    __bf16* wqkv  = (__bf16*)(ws + 16777216);              //  6 MB
    __bf16* wproj = (__bf16*)(ws + 23068672);              //  2 MB
    __bf16* qb    = (__bf16*)(ws + 25165824);              // 16 MB
    __bf16* kb    = (__bf16*)(ws + 41943040);              // 16 MB
    __bf16* vtb   = (__bf16*)(ws + 58720256);              // 16 MB
    __bf16* attb  = xb;                                    // alias: x dead after QKV

    cvt_f32_bf16<<<2048, 256, 0, stream>>>(x,      xb,    4 * 2048 * 1024);
    cvt_f32_bf16<<<768,  256, 0, stream>>>(qkv_w,  wqkv,  3072 * 1024);
    cvt_f32_bf16<<<256,  256, 0, stream>>>(proj_w, wproj, 1024 * 1024);
    qkv_gemm<<<1536, 256, 0, stream>>>(xb, wqkv, qkv_b, qb, kb, vtb);
    attn_kernel<<<512, 256, 0, stream>>>(qb, kb, vtb, attb);
    proj_gemm<<<512, 256, 0, stream>>>(attb, wproj, proj_b, out);
}

// Round 14
// 242.221 us; speedup vs baseline: 1.1987x; 1.1747x over previous
//
#include <hip/hip_runtime.h>
#include <hip/hip_bf16.h>

typedef __bf16 bf16x8 __attribute__((ext_vector_type(8)));
typedef __bf16 bf16x4 __attribute__((ext_vector_type(4)));
typedef float  f32x4  __attribute__((ext_vector_type(4)));

#define MFMA16(a, b, c) __builtin_amdgcn_mfma_f32_16x16x32_bf16((a), (b), (c), 0, 0, 0)
#define GLD16(g, l)                                                              \
    __builtin_amdgcn_global_load_lds(                                            \
        (const __attribute__((address_space(1))) void*)(g),                      \
        (__attribute__((address_space(3))) void*)(l), 16, 0, 0)

// ------------- fused fp32 -> bf16 convert for all three tensors (1 launch) ------
__global__ __launch_bounds__(256) void cvt3_f32_bf16(const float* __restrict__ a, __bf16* __restrict__ oa, int na,
                                                     const float* __restrict__ b, __bf16* __restrict__ ob, int nb,
                                                     const float* __restrict__ c, __bf16* __restrict__ oc, int nc) {
    const int stride = gridDim.x * blockDim.x * 4;
    const int start = (blockIdx.x * blockDim.x + threadIdx.x) * 4;
    for (int i = start; i < na; i += stride) {
        float4 v = *(const float4*)(a + i);
        bf16x4 o; o[0] = (__bf16)v.x; o[1] = (__bf16)v.y; o[2] = (__bf16)v.z; o[3] = (__bf16)v.w;
        *(bf16x4*)(oa + i) = o;
    }
    for (int i = start; i < nb; i += stride) {
        float4 v = *(const float4*)(b + i);
        bf16x4 o; o[0] = (__bf16)v.x; o[1] = (__bf16)v.y; o[2] = (__bf16)v.z; o[3] = (__bf16)v.w;
        *(bf16x4*)(ob + i) = o;
    }
    for (int i = start; i < nc; i += stride) {
        float4 v = *(const float4*)(c + i);
        bf16x4 o; o[0] = (__bf16)v.x; o[1] = (__bf16)v.y; o[2] = (__bf16)v.z; o[3] = (__bf16)v.w;
        *(bf16x4*)(oc + i) = o;
    }
}

// ---------------- QKV GEMM (m97 + XCD swizzle + LDS-transposed V epilogue) -------
// Flat grid 1536, bijective XCD swizzle. Q pre-scaled by 0.125. Each block's 128
// output channels lie entirely in one section (Q/K/V). V blocks transpose their
// 128x128 tile through padded LDS ([128][136], ~2-way writes = free) and emit
// coalesced 16B stores instead of the old 2B x stride-4KB scatter.
__global__ __launch_bounds__(256, 2) void qkv_gemm(const __bf16* __restrict__ X,
                                                   const __bf16* __restrict__ W,
                                                   const float* __restrict__ bias,
                                                   __bf16* __restrict__ Qo,
                                                   __bf16* __restrict__ Ko,
                                                   __bf16* __restrict__ VTo) {
    const int KD = 1024;
    __shared__ __align__(16) char smem[34816];   // As 8K | Bs 8K ; V-epilogue reuses all
    __bf16* As = (__bf16*)smem;
    __bf16* Bs = (__bf16*)(smem + 8192);
    const int tid = threadIdx.x;
    const int lane = tid & 63, w = tid >> 6;
    const int lr = lane & 15, lg = lane >> 4;
    const int orig = blockIdx.x;                       // 0..1535
    const int wgid = (orig & 7) * 192 + (orig >> 3);   // bijective (1536 % 8 == 0)
    const int row0 = (wgid & 63) * 128, col0 = (wgid >> 6) * 128;
    const int wrow = (w >> 1) * 64, wcol = (w & 1) * 64;
    f32x4 acc[4][4] = {};
    const int c0 = tid, c1 = tid + 256;
    const __bf16* ga0 = X + (size_t)(row0 + (c0 >> 2)) * KD + (c0 & 3) * 8;
    const __bf16* ga1 = X + (size_t)(row0 + (c1 >> 2)) * KD + (c1 & 3) * 8;
    const __bf16* gb0 = W + (size_t)(col0 + (c0 >> 2)) * KD + (c0 & 3) * 8;
    const __bf16* gb1 = W + (size_t)(col0 + (c1 >> 2)) * KD + (c1 & 3) * 8;
    for (int k0 = 0; k0 < KD; k0 += 32) {
        __syncthreads();
        GLD16(ga0 + k0, As + c0 * 8);
        GLD16(ga1 + k0, As + c1 * 8);
        GLD16(gb0 + k0, Bs + c0 * 8);
        GLD16(gb1 + k0, Bs + c1 * 8);
        __syncthreads();
        bf16x8 a[4], b[4];
#pragma unroll
        for (int mi = 0; mi < 4; mi++)
            a[mi] = *(const bf16x8*)&As[(wrow + mi * 16 + lr) * 32 + lg * 8];
#pragma unroll
        for (int ni = 0; ni < 4; ni++)
            b[ni] = *(const bf16x8*)&Bs[(wcol + ni * 16 + lr) * 32 + lg * 8];
#pragma unroll
        for (int mi = 0; mi < 4; mi++)
#pragma unroll
            for (int ni = 0; ni < 4; ni++)
                acc[mi][ni] = MFMA16(a[mi], b[ni], acc[mi][ni]);
    }

    if (col0 < 2048) {
        // Q or K section: direct stores (32B-segment coalescing), Q pre-scaled
        const int sec = col0 >> 10;
#pragma unroll
        for (int mi = 0; mi < 4; mi++)
#pragma unroll
            for (int ni = 0; ni < 4; ni++)
#pragma unroll
                for (int r = 0; r < 4; r++) {
                    int m = row0 + wrow + mi * 16 + lg * 4 + r;
                    int n = col0 + wcol + ni * 16 + lr;
                    float v = acc[mi][ni][r] + bias[n];
                    int b_ = m >> 11, t = m & 2047;
                    int c = n & 1023;
                    int h = c >> 6, d = c & 63;
                    int bh = b_ * 16 + h;
                    if (sec == 0) Qo[(size_t)(bh * 2048 + t) * 64 + d] = (__bf16)(v * 0.125f);
                    else          Ko[(size_t)(bh * 2048 + t) * 64 + d] = (__bf16)v;
                }
    } else {
        // V section: transpose 128x128 tile through LDS, coalesced 16B stores
        __syncthreads();                     // all waves done with As/Bs
        __bf16* vt = (__bf16*)smem;          // [128 ch][136] padded
#pragma unroll
        for (int mi = 0; mi < 4; mi++)
#pragma unroll
            for (int ni = 0; ni < 4; ni++) {
                int cl = wcol + ni * 16 + lr;            // channel-local 0..127
                int tl = wrow + mi * 16 + lg * 4;        // token-local base
                int n = col0 + cl;
                bf16x4 pk;
#pragma unroll
                for (int r = 0; r < 4; r++)
                    pk[r] = (__bf16)(acc[mi][ni][r] + bias[n]);
                *(bf16x4*)&vt[cl * 136 + tl] = pk;       // ds_write_b64, ~2-way
            }
        __syncthreads();
        const int b_ = row0 >> 11, t_base = row0 & 2047;
        const int cl = tid >> 1, t0 = (tid & 1) * 64;
        const int c = (col0 + cl) & 1023;
        const int bh = b_ * 16 + (c >> 6), dd = c & 63;
        __bf16* dst = VTo + ((size_t)(bh * 64 + dd)) * 2048 + t_base + t0;
        const __bf16* src = &vt[cl * 136 + t0];
#pragma unroll
        for (int i = 0; i < 8; i++)
            *(bf16x8*)(dst + i * 8) = *(const bf16x8*)(src + i * 8);
    }
}

// ---------------- causal flash attention (r6 champion, Q pre-scaled) -------------
// 512 blocks x 4 waves = 2048 uniform independent waves; wave owns q-tile pair
// {idx, 63-idx} = 33 k-tiles of 64. No k-loop barriers, per-lane defer-max (T13),
// per-lane partial row-sum (single reduce at end), padded P slab (0 conflicts).
// This structure sits on the measured serial-chain floor (~33 x 4.3us).
__global__ __launch_bounds__(256) void attn_kernel(const __bf16* __restrict__ Q,
                                                   const __bf16* __restrict__ Km,
                                                   const __bf16* __restrict__ VT,
                                                   __bf16* __restrict__ ATT) {
    const int T = 2048, D = 64;
    __shared__ __align__(16) __bf16 plds[4][32][68];  // padded: conflict-free
    const int lane = threadIdx.x & 63, w = threadIdx.x >> 6;
    const int lr = lane & 15, lg = lane >> 4;
    // bijective XCD swizzle (512 % 8 == 0): each XCD owns 8 contiguous bh
    const int orig = blockIdx.x;
    const int wgid = (orig & 7) * 64 + (orig >> 3);
    const int bh = wgid >> 3;                 // 8 blocks per bh
    const int idx = (wgid & 7) * 4 + w;       // 0..31
    const int b_ = bh >> 4, hh = bh & 15;
    const __bf16* Qp = Q + (size_t)bh * T * D;
    const __bf16* Kp = Km + (size_t)bh * T * D;
    const __bf16* Vp = VT + (size_t)bh * D * T;

    for (int ph = 0; ph < 2; ++ph) {
        const int j = ph ? 63 - idx : idx;
        const int qrow0 = j * 32;
        bf16x8 qa[2][2];
#pragma unroll
        for (int qt = 0; qt < 2; qt++)
#pragma unroll
            for (int dk = 0; dk < 2; dk++)
                qa[qt][dk] = *(const bf16x8*)(Qp + (size_t)(qrow0 + qt * 16 + lr) * D + dk * 32 + lg * 8);

        float mrow[2][4], lsum[2][4];
#pragma unroll
        for (int qt = 0; qt < 2; qt++)
#pragma unroll
            for (int r = 0; r < 4; r++) { mrow[qt][r] = -1e30f; lsum[qt][r] = 0.f; }
        f32x4 o[2][4] = {};

        const int nkb = (j + 2) >> 1;
        for (int kt0 = 0; kt0 < nkb; ++kt0) {
            const int kb = kt0 * 64;
            bf16x8 kf[4][2];
#pragma unroll
            for (int kt = 0; kt < 4; kt++)
#pragma unroll
                for (int dk = 0; dk < 2; dk++)
                    kf[kt][dk] = *(const bf16x8*)(Kp + (size_t)(kb + kt * 16 + lr) * D + dk * 32 + lg * 8);
            f32x4 s[2][4] = {};
#pragma unroll
            for (int qt = 0; qt < 2; qt++)
#pragma unroll
                for (int kt = 0; kt < 4; kt++)
#pragma unroll
                    for (int dk = 0; dk < 2; dk++)
                        s[qt][kt] = MFMA16(qa[qt][dk], kf[kt][dk], s[qt][kt]);

            // mask + per-lane local max (Q pre-scaled; no cross-lane common path)
            float lmax[2][4];
            int flag = 0;
#pragma unroll
            for (int qt = 0; qt < 2; qt++)
#pragma unroll
                for (int r = 0; r < 4; r++) {
                    const int qq = qrow0 + qt * 16 + lg * 4 + r;
                    float mt = -1e30f;
#pragma unroll
                    for (int kt = 0; kt < 4; kt++) {
                        float v = (kb + kt * 16 + lr <= qq) ? s[qt][kt][r] : -1e30f;
                        s[qt][kt][r] = v;
                        mt = fmaxf(mt, v);
                    }
                    lmax[qt][r] = mt;
                    flag |= (mt > mrow[qt][r] + 8.0f) ? 1 : 0;
                }

            // defer-max (T13): full reduce + rescale only when some row grew > 8
            if (__any(flag)) {
#pragma unroll
                for (int qt = 0; qt < 2; qt++)
#pragma unroll
                    for (int r = 0; r < 4; r++) {
                        float mt = lmax[qt][r];
#pragma unroll
                        for (int off = 1; off < 16; off <<= 1)
                            mt = fmaxf(mt, __shfl_xor(mt, off));
                        float mnew = fmaxf(mrow[qt][r], mt);
                        float al = __expf(mrow[qt][r] - mnew);
                        mrow[qt][r] = mnew;
                        lsum[qt][r] *= al;
#pragma unroll
                        for (int dt = 0; dt < 4; dt++) o[qt][dt][r] *= al;
                    }
            }

            // exp + per-lane partial row-sum
#pragma unroll
            for (int qt = 0; qt < 2; qt++)
#pragma unroll
                for (int r = 0; r < 4; r++) {
                    float rs = 0.f;
#pragma unroll
                    for (int kt = 0; kt < 4; kt++) {
                        float p = __expf(s[qt][kt][r] - mrow[qt][r]);
                        s[qt][kt][r] = p;
                        rs += p;
                    }
                    lsum[qt][r] += rs;
                }

            // P -> padded LDS slab (conflict-free) -> A-fragments
#pragma unroll
            for (int qt = 0; qt < 2; qt++)
#pragma unroll
                for (int kt = 0; kt < 4; kt++)
#pragma unroll
                    for (int r = 0; r < 4; r++)
                        plds[w][qt * 16 + lg * 4 + r][kt * 16 + lr] = (__bf16)s[qt][kt][r];

            bf16x8 pa[2][2];
#pragma unroll
            for (int qt = 0; qt < 2; qt++)
#pragma unroll
                for (int kh = 0; kh < 2; kh++)
                    pa[qt][kh] = *(const bf16x8*)&plds[w][qt * 16 + lr][kh * 32 + lg * 8];

#pragma unroll
            for (int kh = 0; kh < 2; kh++) {
                bf16x8 vf[4];
#pragma unroll
                for (int dt = 0; dt < 4; dt++)
                    vf[dt] = *(const bf16x8*)(Vp + (size_t)(dt * 16 + lr) * T + kb + kh * 32 + lg * 8);
#pragma unroll
                for (int qt = 0; qt < 2; qt++)
#pragma unroll
                    for (int dt = 0; dt < 4; dt++)
                        o[qt][dt] = MFMA16(pa[qt][kh], vf[dt], o[qt][dt]);
            }
        }

        // final row-sum reduce (once per panel) + normalize + store
#pragma unroll
        for (int qt = 0; qt < 2; qt++)
#pragma unroll
            for (int r = 0; r < 4; r++) {
                float rs = lsum[qt][r];
#pragma unroll
                for (int off = 1; off < 16; off <<= 1)
                    rs += __shfl_xor(rs, off);
                lsum[qt][r] = 1.0f / rs;
            }
#pragma unroll
        for (int qt = 0; qt < 2; qt++)
#pragma unroll
            for (int dt = 0; dt < 4; dt++)
#pragma unroll
                for (int r = 0; r < 4; r++) {
                    int qq = qrow0 + qt * 16 + lg * 4 + r;
                    int dd = dt * 16 + lr;
                    float val = o[qt][dt][r] * lsum[qt][r];
                    ATT[(size_t)(b_ * 2048 + qq) * 1024 + hh * 64 + dd] = (__bf16)val;
                }
    }
}

// ---------------- proj GEMM (m97 structure + XCD-chunked swizzle) ----------------
__global__ __launch_bounds__(256, 2) void proj_gemm(const __bf16* __restrict__ A,
                                                    const __bf16* __restrict__ W,
                                                    const float* __restrict__ bias,
                                                    float* __restrict__ out) {
    const int KD = 1024;
    __shared__ __align__(16) __bf16 As[128 * 32];
    __shared__ __align__(16) __bf16 Bs[128 * 32];
    const int tid = threadIdx.x;
    const int lane = tid & 63, w = tid >> 6;
    const int lr = lane & 15, lg = lane >> 4;
    const int orig = blockIdx.x;                       // 0..511
    const int wgid = (orig & 7) * 64 + (orig >> 3);    // XCD x owns col-tile x
    const int row0 = (wgid & 63) * 128, col0 = (wgid >> 6) * 128;
    const int wrow = (w >> 1) * 64, wcol = (w & 1) * 64;
    f32x4 acc[4][4] = {};
    const int c0 = tid, c1 = tid + 256;
    const __bf16* ga0 = A + (size_t)(row0 + (c0 >> 2)) * KD + (c0 & 3) * 8;
    const __bf16* ga1 = A + (size_t)(row0 + (c1 >> 2)) * KD + (c1 & 3) * 8;
    const __bf16* gb0 = W + (size_t)(col0 + (c0 >> 2)) * KD + (c0 & 3) * 8;
    const __bf16* gb1 = W + (size_t)(col0 + (c1 >> 2)) * KD + (c1 & 3) * 8;
    for (int k0 = 0; k0 < KD; k0 += 32) {
        __syncthreads();
        GLD16(ga0 + k0, As + c0 * 8);
        GLD16(ga1 + k0, As + c1 * 8);
        GLD16(gb0 + k0, Bs + c0 * 8);
        GLD16(gb1 + k0, Bs + c1 * 8);
        __syncthreads();
        bf16x8 a[4], b[4];
#pragma unroll
        for (int mi = 0; mi < 4; mi++)
            a[mi] = *(const bf16x8*)&As[(wrow + mi * 16 + lr) * 32 + lg * 8];
#pragma unroll
        for (int ni = 0; ni < 4; ni++)
            b[ni] = *(const bf16x8*)&Bs[(wcol + ni * 16 + lr) * 32 + lg * 8];
#pragma unroll
        for (int mi = 0; mi < 4; mi++)
#pragma unroll
            for (int ni = 0; ni < 4; ni++)
                acc[mi][ni] = MFMA16(a[mi], b[ni], acc[mi][ni]);
    }
#pragma unroll
    for (int mi = 0; mi < 4; mi++)
#pragma unroll
        for (int ni = 0; ni < 4; ni++)
#pragma unroll
            for (int r = 0; r < 4; r++) {
                int m = row0 + wrow + mi * 16 + lg * 4 + r;
                int n = col0 + wcol + ni * 16 + lr;
                out[(size_t)m * 1024 + n] = acc[mi][ni][r] + bias[n];
            }
}

extern "C" void kernel_launch(void* const* d_in, const int* in_sizes, int n_in,
                              void* d_out, int out_size, void* d_ws, size_t ws_size,
                              hipStream_t stream) {
    const float* x      = (const float*)d_in[0];
    const float* qkv_w  = (const float*)d_in[1];
    const float* qkv_b  = (const float*)d_in[2];
    const float* proj_w = (const float*)d_in[3];
    const float* proj_b = (const float*)d_in[4];
    float* out = (float*)d_out;
    char* ws = (char*)d_ws;

    // workspace layout (72 MB total)
    __bf16* xb    = (__bf16*)(ws);                         // 16 MB (reused as attb)
    __bf16* wqkv  = (__bf16*)(ws + 16777216);              //  6 MB
    __bf16* wproj = (__bf16*)(ws + 23068672);              //  2 MB
    __bf16* qb    = (__bf16*)(ws + 25165824);              // 16 MB
    __bf16* kb    = (__bf16*)(ws + 41943040);              // 16 MB
    __bf16* vtb   = (__bf16*)(ws + 58720256);              // 16 MB
    __bf16* attb  = xb;                                    // alias: x dead after QKV

    cvt3_f32_bf16<<<2048, 256, 0, stream>>>(x, xb, 4 * 2048 * 1024,
                                            qkv_w, wqkv, 3072 * 1024,
                                            proj_w, wproj, 1024 * 1024);
    qkv_gemm<<<1536, 256, 0, stream>>>(xb, wqkv, qkv_b, qb, kb, vtb);
    attn_kernel<<<512, 256, 0, stream>>>(qb, kb, vtb, attb);
    proj_gemm<<<512, 256, 0, stream>>>(attb, wproj, proj_b, out);
}